// Round 1
// baseline (7723.179 us; speedup 1.0000x reference)
//
#include <hip/hip_runtime.h>
#include <math.h>

#define Hc   128
#define Bc   512
#define Tc   64
#define NXc  518
#define NCELL (518*518)
#define NEV  (Bc*Tc)            // 32768 events
#define SWc  2

// ---------------- precompute kernels ----------------

// Build per-cell linked list of write events. e = t*512 + b (monotone in (t,b)).
__global__ void k_build(const float* __restrict__ feat, int* __restrict__ head,
                        int* __restrict__ nxt, int* __restrict__ cellxy) {
    int gid = blockIdx.x * 256 + threadIdx.x;
    if (gid >= NEV) return;
    int b = gid >> 6, t = gid & 63;
    int base = (b * Tc + t) * 4;
    int gx = (int)feat[base + 2] + SWc;
    int gy = (int)feat[base + 3] + SWc;
    gx = min(max(gx, 0), NXc - 1);
    gy = min(max(gy, 0), NXc - 1);
    int cell = gx * NXc + gy;
    int e = t * Bc + b;
    cellxy[e] = (gx << 16) | gy;
    int old = atomicExch(&head[cell], e);   // list order irrelevant: resolver takes max
    nxt[e] = old;
}

// For each read (b,t,k): find latest write event with t_w < t (ties: max b). -1 if none.
__global__ void k_resolve(const int* __restrict__ head, const int* __restrict__ nxt,
                          const int* __restrict__ cellxy, int* __restrict__ dep) {
    int gid = blockIdx.x * 256 + threadIdx.x;
    if (gid >= NEV * 25) return;
    int r = gid / 25, k = gid - r * 25;
    int t = r & 63, b = r >> 6;
    int e0 = t * Bc + b;
    int xy = cellxy[e0];
    int gx = xy >> 16, gy = xy & 0xffff;
    int cx = gx + (k / 5) - SWc, cy = gy + (k % 5) - SWc;
    cx = min(max(cx, 0), NXc - 1);
    cy = min(max(cy, 0), NXc - 1);
    int cell = cx * NXc + cy;
    int best = -1;
    for (int e = head[cell]; e >= 0; e = nxt[e])
        if ((e >> 9) < t && e > best) best = e;
    dep[r * 25 + k] = best;
}

// ---------------- main persistent dataflow kernel ----------------

// LDS carve (floats)
#define L_WOUT   (128*257)
constexpr int LDS_FLOATS = L_WOUT + 256 + 1024 + 256 + 256 + 256 + 256 + 256 + 64 + 1024 + 512 + 8 + 128 + 64;
constexpr int LDS_BYTES  = LDS_FLOATS * 4;

__global__ __launch_bounds__(512, 2)
void step_main(const float* __restrict__ feat, const float* __restrict__ Wih,
               const float* __restrict__ bih,  const float* __restrict__ Whh,
               const float* __restrict__ bhh,  const float* __restrict__ Wout,
               const float* __restrict__ bout, const int*   __restrict__ seq,
               const int*   __restrict__ dep,  float* __restrict__ vbuf,
               unsigned*    __restrict__ flags, float* __restrict__ dout) {
    extern __shared__ float lds[];
    float* WoutL = lds;                 // 128*257 (pad 257 -> conflict-free)
    float* hid   = WoutL + L_WOUT;      // 2*128
    float* g     = hid   + 256;         // 2*512   (reused as cat[2][256] later)
    float* gin   = g     + 1024;        // 2*128
    float* qv    = gin   + 256;         // 2*128
    float* ug    = qv    + 256;
    float* sg    = ug    + 256;
    float* ctr   = sg    + 256;         // 2*128
    float* scor  = ctr   + 256;         // 2*32
    float* pmix  = scor  + 64;          // 2*4*128
    float* part  = pmix  + 1024;        // 2*2*128
    float* fxy   = part  + 512;         // 2*4
    float* boutL = fxy   + 8;           // 128
    int*   depv  = (int*)(boutL + 128); // 2*25 (+pad)

    const int tid = threadIdx.x;
    const int blk = blockIdx.x;
    const int lane = tid & 63;
    const int w  = tid >> 6;            // wave 0..7
    const int wj = w >> 2;              // chain handled by this wave
    const int ww = w & 3;               // wave-within-chain

    // persistent per-thread state: W_hh row (128 floats = 32 float4), biases, W_ih row
    const int o = tid;                  // 0..511
    float4 wr[32];
    {
        const float4* wp = (const float4*)(Whh + (size_t)o * Hc);
        #pragma unroll
        for (int i = 0; i < 32; ++i) wr[i] = wp[i];
    }
    const float bihr = bih[o], bhhr = bhh[o];
    const float wih0 = Wih[o * 2 + 0], wih1 = Wih[o * 2 + 1];
    const int chunk = o >> 7;

    // stage W_out (padded) + b_out into LDS
    for (int i = tid; i < 128 * 256; i += 512)
        WoutL[(i >> 8) * 257 + (i & 255)] = Wout[i];
    if (tid < 128) boutL[tid] = bout[tid];
    if (tid < 256) hid[tid] = 0.f;
    if (tid < 8) { int j = tid >> 2, c = tid & 3;
                   fxy[tid] = feat[((size_t)(blk * 2 + j) * Tc + 0) * 4 + c]; (void)j; }
    int sidx = -2;
    if (tid < 256) { int j = tid >> 7; int s = seq[blk * 2 + j]; sidx = max(s, 1) - 1; }
    __syncthreads();

    const float NEG_INF = -__builtin_inff();

    for (int t = 0; t < Tc; ++t) {
        // ---- P1: gh for both chains (W_hh in regs, hidden broadcast from LDS) ----
        float accs[2];
        #pragma unroll
        for (int j = 0; j < 2; ++j) {
            const float4* hp = (const float4*)(hid + j * 128);
            float a0 = 0.f, a1 = 0.f, a2 = 0.f, a3 = 0.f;
            #pragma unroll
            for (int i = 0; i < 32; ++i) {
                float4 h4 = hp[i], w4 = wr[i];
                a0 = fmaf(w4.x, h4.x, a0); a1 = fmaf(w4.y, h4.y, a1);
                a2 = fmaf(w4.z, h4.z, a2); a3 = fmaf(w4.w, h4.w, a3);
            }
            accs[j] = (a0 + a1) + (a2 + a3);
        }
        #pragma unroll
        for (int j = 0; j < 2; ++j) {
            float gi = fmaf(wih0, fxy[j * 4 + 0], wih1 * fxy[j * 4 + 1]);
            float val = accs[j] + bhhr + ((chunk == 2) ? 0.f : (gi + bihr));
            g[j * 512 + o] = val;
            if (chunk == 2) gin[j * 128 + (o & 127)] = gi + bihr;
        }
        __syncthreads();

        // ---- P2: gates (t<256) ; dep fetch (t>=256) ----
        if (tid < 256) {
            int j = tid >> 7, h = tid & 127;
            float gr = g[j * 512 + h], gu = g[j * 512 + 128 + h];
            float gn = g[j * 512 + 256 + h], gs = g[j * 512 + 384 + h];
            float rr = 1.f / (1.f + expf(-gr));
            float uu = 1.f / (1.f + expf(-gu));
            float ss = 1.f / (1.f + expf(-gs));
            float nn = tanhf(gin[j * 128 + h] + rr * gn);
            qv[j * 128 + h] = nn; ug[j * 128 + h] = uu; sg[j * 128 + h] = ss;
            ctr[j * 128 + h] = 0.f;
        } else {
            int idx = tid - 256;
            if (idx < 50) {
                int j = idx / 25, k = idx - j * 25;
                depv[j * 25 + k] = dep[(((size_t)(blk * 2 + j)) * Tc + t) * 25 + k];
            }
        }
        __syncthreads();

        // ---- P3: spin-wait on producers (lane0 per wave, wave-uniform dep) ----
        for (int kk = 0; kk < 7; ++kk) {
            int k = ww + 4 * kk;
            if (k < 25) {
                int e = depv[wj * 25 + k];
                if (e >= 0 && lane == 0) {
                    while (__hip_atomic_load(&flags[e], __ATOMIC_RELAXED,
                                             __HIP_MEMORY_SCOPE_AGENT) == 0u)
                        __builtin_amdgcn_s_sleep(2);
                }
            }
        }
        __syncthreads();
        __threadfence();   // acquire: invalidate caches before reading remote vbuf

        // ---- P4: gather ctx + scores (lane l holds h=2l,2l+1) ----
        float2 valk[7];
        #pragma unroll
        for (int kk = 0; kk < 7; ++kk) {
            int k = ww + 4 * kk;
            valk[kk].x = 0.f; valk[kk].y = 0.f;
            if (k < 25) {
                int e = depv[wj * 25 + k];
                float sc;
                if (e >= 0) {
                    float2 v = ((const float2*)(vbuf + (size_t)e * Hc))[lane];
                    valk[kk] = v;
                    float d = fmaf(v.x, qv[wj * 128 + 2 * lane],
                                   v.y * qv[wj * 128 + 2 * lane + 1]);
                    #pragma unroll
                    for (int m = 1; m < 64; m <<= 1) d += __shfl_xor(d, m, 64);
                    sc = (d == 0.f) ? NEG_INF : d;
                    if (k == 12) { ctr[wj * 128 + 2 * lane]     = v.x;
                                   ctr[wj * 128 + 2 * lane + 1] = v.y; }
                } else sc = NEG_INF;
                if (lane == 0) scor[wj * 32 + k] = sc;
            }
        }
        __syncthreads();

        // ---- P5: softmax over 25 (wave0, 32-lane group per chain) ----
        if (tid < 64) {
            int j = lane >> 5, kk2 = lane & 31;
            float v = (kk2 < 25) ? scor[j * 32 + kk2] : NEG_INF;
            float m = v;
            #pragma unroll
            for (int mm = 1; mm < 32; mm <<= 1) m = fmaxf(m, __shfl_xor(m, mm, 64));
            float a;
            if (m == NEG_INF) a = 0.f;
            else {
                float p = (v == NEG_INF) ? 0.f : expf(v - m);
                float ssum = p;
                #pragma unroll
                for (int mm = 1; mm < 32; mm <<= 1) ssum += __shfl_xor(ssum, mm, 64);
                a = p / ssum;
            }
            if (kk2 < 25) scor[j * 32 + kk2] = a;
        }
        __syncthreads();

        // ---- P6: mix partial sums per wave ----
        {
            float pm0 = 0.f, pm1 = 0.f;
            #pragma unroll
            for (int kk = 0; kk < 7; ++kk) {
                int k = ww + 4 * kk;
                if (k < 25) {
                    int e = depv[wj * 25 + k];
                    if (e >= 0) {
                        float a = scor[wj * 32 + k];
                        pm0 = fmaf(a, valk[kk].x, pm0);
                        pm1 = fmaf(a, valk[kk].y, pm1);
                    }
                }
            }
            pmix[(wj * 4 + ww) * 128 + 2 * lane]     = pm0;
            pmix[(wj * 4 + ww) * 128 + 2 * lane + 1] = pm1;
        }
        __syncthreads();

        // ---- P7a: cat = [mix, q] (reuse g) ----
        if (tid < 256) {
            int j = tid >> 7, h = tid & 127;
            float mix = pmix[(j * 4 + 0) * 128 + h] + pmix[(j * 4 + 1) * 128 + h]
                      + pmix[(j * 4 + 2) * 128 + h] + pmix[(j * 4 + 3) * 128 + h];
            g[j * 512 + h] = mix;
            g[j * 512 + 128 + h] = qv[j * 128 + h];
        }
        __syncthreads();

        // ---- P7b: W_out half-dots from LDS ----
        {
            int j = tid >> 8, rem = tid & 255, oo = rem & 127, half = rem >> 7;
            const float* wrow = &WoutL[oo * 257 + half * 128];
            const float* cc   = &g[j * 512 + half * 128];
            float a0 = 0.f, a1 = 0.f, a2 = 0.f, a3 = 0.f;
            #pragma unroll
            for (int c = 0; c < 128; c += 4) {
                a0 = fmaf(wrow[c],     cc[c],     a0);
                a1 = fmaf(wrow[c + 1], cc[c + 1], a1);
                a2 = fmaf(wrow[c + 2], cc[c + 2], a2);
                a3 = fmaf(wrow[c + 3], cc[c + 3], a3);
            }
            part[(j * 2 + half) * 128 + oo] = (a0 + a1) + (a2 + a3);
        }
        __syncthreads();

        // ---- P7c: epilogue + vbuf/dout stores ; prefetch next fxy ----
        if (tid < 256) {
            int j = tid >> 7, h = tid & 127;
            int b = blk * 2 + j;
            float v = part[(j * 2 + 0) * 128 + h] + part[(j * 2 + 1) * 128 + h] + boutL[h];
            float at = tanhf(v);
            float n = qv[j * 128 + h], uu = ug[j * 128 + h], ss = sg[j * 128 + h];
            float hv = hid[j * 128 + h];
            float curr = fmaf(ss, at, n);
            float outv = curr + uu * (hv - curr);
            hid[j * 128 + h] = outv;
            float upd = fmaf(ss, ctr[j * 128 + h], (1.f - ss) * outv);
            vbuf[((size_t)(t * Bc + b)) * Hc + h] = upd;
            if (sidx == t) dout[(size_t)b * Hc + h] = outv;
        } else {
            int idx = tid - 256;
            if (idx < 8 && t < Tc - 1) {
                int j = idx >> 2, c = idx & 3;
                fxy[idx] = feat[((size_t)(blk * 2 + j) * Tc + (t + 1)) * 4 + c];
            }
        }
        __threadfence();   // release: push vbuf writes to device-coherent point
        __syncthreads();
        if (tid == 0 || tid == 256) {
            int j = tid >> 8;
            __hip_atomic_store(&flags[t * Bc + blk * 2 + j], 1u,
                               __ATOMIC_RELAXED, __HIP_MEMORY_SCOPE_AGENT);
        }
        // no extra sync needed: next-step LDS reads are covered by the sync above
    }
}

// ---------------- host launch ----------------

extern "C" void kernel_launch(void* const* d_in, const int* in_sizes, int n_in,
                              void* d_out, int out_size, void* d_ws, size_t ws_size,
                              hipStream_t stream) {
    const float* feat = (const float*)d_in[0];
    const float* Wih  = (const float*)d_in[1];
    const float* bih  = (const float*)d_in[2];
    const float* Whh  = (const float*)d_in[3];
    const float* bhh  = (const float*)d_in[4];
    const float* Wout = (const float*)d_in[5];
    const float* bout = (const float*)d_in[6];
    const int*   seq  = (const int*)d_in[7];

    char* ws = (char*)d_ws;
    size_t off = 0;
    auto carve = [&](size_t bytes) { char* p = ws + off; off += (bytes + 511) & ~(size_t)511; return p; };
    float*    vbuf   = (float*)   carve((size_t)NEV * Hc * 4);   // 16.8 MB
    int*      head   = (int*)     carve((size_t)NCELL * 4);      // 1.07 MB
    int*      nxt    = (int*)     carve((size_t)NEV * 4);
    int*      cellxy = (int*)     carve((size_t)NEV * 4);
    int*      dep    = (int*)     carve((size_t)NEV * 25 * 4);   // 3.3 MB
    unsigned* flags  = (unsigned*)carve((size_t)NEV * 4);

    hipMemsetAsync(head, 0xFF, (size_t)NCELL * 4, stream);   // -1
    hipMemsetAsync(flags, 0, (size_t)NEV * 4, stream);

    k_build<<<(NEV + 255) / 256, 256, 0, stream>>>(feat, head, nxt, cellxy);
    k_resolve<<<(NEV * 25 + 255) / 256, 256, 0, stream>>>(head, nxt, cellxy, dep);

    hipFuncSetAttribute((const void*)step_main,
                        hipFuncAttributeMaxDynamicSharedMemorySize, LDS_BYTES);
    step_main<<<256, 512, LDS_BYTES, stream>>>(feat, Wih, bih, Whh, bhh, Wout, bout,
                                               seq, dep, vbuf, flags, (float*)d_out);
}

// Round 2
// 2057.724 us; speedup vs baseline: 3.7533x; 3.7533x over previous
//
#include <hip/hip_runtime.h>
#include <math.h>

#define Hc   128
#define Bc   512
#define Tc   64
#define NXc  518
#define NCELL (518*518)
#define NEV  (Bc*Tc)            // 32768 events
#define SWc  2

// ---------------- precompute kernels ----------------

__global__ void k_build(const float* __restrict__ feat, int* __restrict__ head,
                        int* __restrict__ nxt, int* __restrict__ cellxy) {
    int gid = blockIdx.x * 256 + threadIdx.x;
    if (gid >= NEV) return;
    int b = gid >> 6, t = gid & 63;
    int base = (b * Tc + t) * 4;
    int gx = (int)feat[base + 2] + SWc;
    int gy = (int)feat[base + 3] + SWc;
    gx = min(max(gx, 0), NXc - 1);
    gy = min(max(gy, 0), NXc - 1);
    int cell = gx * NXc + gy;
    int e = t * Bc + b;
    cellxy[e] = (gx << 16) | gy;
    int old = atomicExch(&head[cell], e);
    nxt[e] = old;
}

__global__ void k_resolve(const int* __restrict__ head, const int* __restrict__ nxt,
                          const int* __restrict__ cellxy, int* __restrict__ dep) {
    int gid = blockIdx.x * 256 + threadIdx.x;
    if (gid >= NEV * 25) return;
    int r = gid / 25, k = gid - r * 25;
    int t = r & 63, b = r >> 6;
    int e0 = t * Bc + b;
    int xy = cellxy[e0];
    int gx = xy >> 16, gy = xy & 0xffff;
    int cx = gx + (k / 5) - SWc, cy = gy + (k % 5) - SWc;
    cx = min(max(cx, 0), NXc - 1);
    cy = min(max(cy, 0), NXc - 1);
    int cell = cx * NXc + cy;
    int best = -1;
    for (int e = head[cell]; e >= 0; e = nxt[e])
        if ((e >> 9) < t && e > best) best = e;
    dep[r * 25 + k] = best;
}

// ---------------- main persistent dataflow kernel ----------------

// W_out LDS row stride 260 floats: 1040 B (16B-aligned for b128; 260%32=4 ->
// 32 oo-rows spread over all banks with min 8 words/bank -> balanced b128)
#define WSTRIDE 260
#define L_WOUT  (128 * WSTRIDE)
constexpr int LDS_FLOATS = L_WOUT + 256 + 1024 + 256 + 256 + 256 + 256 + 256 + 64 + 1024 + 16 + 128 + 64;
constexpr int LDS_BYTES  = LDS_FLOATS * 4;

__device__ __forceinline__ float2 load_f2_coherent(const float* p) {
    unsigned long long raw = __hip_atomic_load((const unsigned long long*)p,
                                               __ATOMIC_RELAXED, __HIP_MEMORY_SCOPE_AGENT);
    float2 v;
    __builtin_memcpy(&v, &raw, 8);
    return v;
}

__global__ __launch_bounds__(512, 2)
void step_main(const float* __restrict__ feat, const float* __restrict__ Wih,
               const float* __restrict__ bih,  const float* __restrict__ Whh,
               const float* __restrict__ bhh,  const float* __restrict__ Wout,
               const float* __restrict__ bout, const int*   __restrict__ seq,
               const int*   __restrict__ dep,  float* __restrict__ vbuf,
               unsigned*    __restrict__ flags, float* __restrict__ dout) {
    extern __shared__ float lds[];
    float* WoutL = lds;                 // 128*260
    float* hid   = WoutL + L_WOUT;      // 2*128
    float* g     = hid   + 256;         // 2*512 (reused as cat[2][256])
    float* gin   = g     + 1024;        // 2*128
    float* qv    = gin   + 256;         // 2*128
    float* ug    = qv    + 256;
    float* sg    = ug    + 256;
    float* ctr   = sg    + 256;         // 2*128
    float* scor  = ctr   + 256;         // 2*32
    float* pmix  = scor  + 64;          // 2*4*128
    float* fxy   = pmix  + 1024;        // 2 parities * 8
    float* boutL = fxy   + 16;          // 128
    int*   depv  = (int*)(boutL + 128); // 2*25 (+pad)

    const int tid  = threadIdx.x;
    const int blk  = blockIdx.x;
    const int lane = tid & 63;
    const int w    = tid >> 6;          // wave 0..7
    const int wj   = w >> 2;            // chain of this wave
    const int ww   = w & 3;             // wave-within-chain

    // persistent per-thread state: one W_hh row (128 floats), biases, W_ih row
    const int o = tid;
    float4 wr[32];
    {
        const float4* wp = (const float4*)(Whh + (size_t)o * Hc);
        #pragma unroll
        for (int i = 0; i < 32; ++i) wr[i] = wp[i];
    }
    const float bihr = bih[o], bhhr = bhh[o];
    const float wih0 = Wih[o * 2 + 0], wih1 = Wih[o * 2 + 1];
    const int chunk = o >> 7;

    // stage W_out (stride-260) + b_out
    for (int i = tid; i < 128 * 256; i += 512)
        WoutL[(i >> 8) * WSTRIDE + (i & 255)] = Wout[i];
    if (tid < 128) boutL[tid] = bout[tid];
    if (tid < 256) hid[tid] = 0.f;
    if (tid < 8) { int j = tid >> 2, c = tid & 3;
                   fxy[tid] = feat[((size_t)(blk * 2 + j) * Tc + 0) * 4 + c]; }
    int sidx;
    { int j2 = tid >> 8; sidx = max(seq[blk * 2 + j2], 1) - 1; }
    __syncthreads();

    const float NEG_INF = -__builtin_inff();

    for (int t = 0; t < Tc; ++t) {
        const float* fx = fxy + (t & 1) * 8;

        // ---- P1: gh dots (W_hh in regs, hid broadcast); dep + fxy prefetch ----
        float accs[2];
        #pragma unroll
        for (int j = 0; j < 2; ++j) {
            const float4* hp = (const float4*)(hid + j * 128);
            float a0 = 0.f, a1 = 0.f, a2 = 0.f, a3 = 0.f;
            #pragma unroll
            for (int i = 0; i < 32; ++i) {
                float4 h4 = hp[i], w4 = wr[i];
                a0 = fmaf(w4.x, h4.x, a0); a1 = fmaf(w4.y, h4.y, a1);
                a2 = fmaf(w4.z, h4.z, a2); a3 = fmaf(w4.w, h4.w, a3);
            }
            accs[j] = (a0 + a1) + (a2 + a3);
        }
        #pragma unroll
        for (int j = 0; j < 2; ++j) {
            float gi  = fmaf(wih0, fx[j * 4 + 0], wih1 * fx[j * 4 + 1]);
            float val = accs[j] + bhhr + ((chunk == 2) ? 0.f : (gi + bihr));
            g[j * 512 + o] = val;
            if (chunk == 2) gin[j * 128 + (o & 127)] = gi + bihr;
        }
        if (tid < 50) {
            int j = (tid >= 25), k = tid - j * 25;
            depv[tid] = dep[(((size_t)(blk * 2 + j)) * Tc + t) * 25 + k];
        }
        if (tid >= 56 && tid < 64 && t + 1 < Tc) {
            int idx = tid - 56, j = idx >> 2, c = idx & 3;
            fxy[((t + 1) & 1) * 8 + idx] =
                feat[((size_t)(blk * 2 + j) * Tc + (t + 1)) * 4 + c];
        }
        __syncthreads();

        // ---- P2: gates (tid<256) + spin-wait on producers (lane0/wave) ----
        if (tid < 256) {
            int j = tid >> 7, h = tid & 127;
            float gr = g[j * 512 + h],       gu = g[j * 512 + 128 + h];
            float gn = g[j * 512 + 256 + h], gs = g[j * 512 + 384 + h];
            float rr = 1.f / (1.f + __expf(-gr));
            float uu = 1.f / (1.f + __expf(-gu));
            float ss = 1.f / (1.f + __expf(-gs));
            float nn = tanhf(gin[j * 128 + h] + rr * gn);
            qv[j * 128 + h] = nn; ug[j * 128 + h] = uu; sg[j * 128 + h] = ss;
            ctr[j * 128 + h] = 0.f;
        }
        if (lane == 0) {
            #pragma unroll
            for (int kk = 0; kk < 7; ++kk) {
                int k = ww + 4 * kk;
                if (k < 25) {
                    int e = depv[wj * 25 + k];
                    if (e >= 0) {
                        while (__hip_atomic_load(&flags[e], __ATOMIC_RELAXED,
                                                 __HIP_MEMORY_SCOPE_AGENT) == 0u)
                            __builtin_amdgcn_s_sleep(1);
                    }
                }
            }
        }
        __syncthreads();

        // ---- P4: gather (coherent sc1 loads) + scores ----
        float2 valk[7];
        #pragma unroll
        for (int kk = 0; kk < 7; ++kk) {
            int k = ww + 4 * kk;
            valk[kk] = make_float2(0.f, 0.f);
            if (k < 25) {
                int e = depv[wj * 25 + k];
                float sc;
                if (e >= 0) {
                    float2 v = load_f2_coherent(vbuf + (size_t)e * Hc + 2 * lane);
                    valk[kk] = v;
                    float d = fmaf(v.x, qv[wj * 128 + 2 * lane],
                                   v.y * qv[wj * 128 + 2 * lane + 1]);
                    #pragma unroll
                    for (int m = 1; m < 64; m <<= 1) d += __shfl_xor(d, m, 64);
                    sc = (d == 0.f) ? NEG_INF : d;
                    if (k == 12) { ctr[wj * 128 + 2 * lane]     = v.x;
                                   ctr[wj * 128 + 2 * lane + 1] = v.y; }
                } else sc = NEG_INF;
                if (lane == 0) scor[wj * 32 + k] = sc;
            }
        }
        __syncthreads();

        // ---- P56: redundant per-wave softmax (32-lane groups) + mix partials ----
        {
            int k2 = lane & 31;
            float v = (k2 < 25) ? scor[wj * 32 + k2] : NEG_INF;
            float m = v;
            #pragma unroll
            for (int mm = 1; mm < 32; mm <<= 1) m = fmaxf(m, __shfl_xor(m, mm, 64));
            float a = 0.f;
            if (m != NEG_INF) {
                float p = (v == NEG_INF) ? 0.f : __expf(v - m);
                float s = p;
                #pragma unroll
                for (int mm = 1; mm < 32; mm <<= 1) s += __shfl_xor(s, mm, 64);
                a = p / s;
            }
            float pm0 = 0.f, pm1 = 0.f;
            #pragma unroll
            for (int kk = 0; kk < 7; ++kk) {
                int k = ww + 4 * kk;
                if (k < 25) {
                    float ak = __shfl(a, k, 64);
                    pm0 = fmaf(ak, valk[kk].x, pm0);
                    pm1 = fmaf(ak, valk[kk].y, pm1);
                }
            }
            pmix[(wj * 4 + ww) * 128 + 2 * lane]     = pm0;
            pmix[(wj * 4 + ww) * 128 + 2 * lane + 1] = pm1;
        }
        __syncthreads();

        // ---- P7a: cat = [mix, q] into g ----
        if (tid < 256) {
            int j = tid >> 7, h = tid & 127;
            float mix = pmix[(j * 4 + 0) * 128 + h] + pmix[(j * 4 + 1) * 128 + h]
                      + pmix[(j * 4 + 2) * 128 + h] + pmix[(j * 4 + 3) * 128 + h];
            g[j * 512 + h] = mix;
            g[j * 512 + 128 + h] = qv[j * 128 + h];
        }
        __syncthreads();

        // ---- P7b: W_out half-dots (lane-pair halves) + fused epilogue ----
        {
            int j = tid >> 8, idx = tid & 255, oo = idx >> 1, half = idx & 1;
            const float4* wrow4 = (const float4*)(WoutL + oo * WSTRIDE + half * 128);
            const float4* cc4   = (const float4*)(g + j * 512 + half * 128);
            float a0 = 0.f, a1 = 0.f, a2 = 0.f, a3 = 0.f;
            #pragma unroll
            for (int c = 0; c < 32; ++c) {
                float4 wv = wrow4[c], cv = cc4[c];
                a0 = fmaf(wv.x, cv.x, a0); a1 = fmaf(wv.y, cv.y, a1);
                a2 = fmaf(wv.z, cv.z, a2); a3 = fmaf(wv.w, cv.w, a3);
            }
            float partial = (a0 + a1) + (a2 + a3);
            float tot = partial + __shfl_xor(partial, 1, 64);
            float vv  = tot + boutL[oo];
            float at  = tanhf(vv);
            int h = oo;
            float n  = qv[j * 128 + h], uu = ug[j * 128 + h];
            float ss = sg[j * 128 + h], hv = hid[j * 128 + h];
            float curr = fmaf(ss, at, n);
            float outv = curr + uu * (hv - curr);
            if (half) {
                hid[j * 128 + h] = outv;
            } else {
                float upd = fmaf(ss, ctr[j * 128 + h], (1.f - ss) * outv);
                __hip_atomic_store(&vbuf[((size_t)(t * Bc + blk * 2 + j)) * Hc + h],
                                   upd, __ATOMIC_RELAXED, __HIP_MEMORY_SCOPE_AGENT);
                if (sidx == t) dout[(size_t)(blk * 2 + j) * Hc + h] = outv;
            }
        }
        __syncthreads();   // drains vmcnt(0): vbuf stores complete before flags
        if (tid == 0 || tid == 256) {
            int j = tid >> 8;
            __hip_atomic_store(&flags[t * Bc + blk * 2 + j], 1u,
                               __ATOMIC_RELAXED, __HIP_MEMORY_SCOPE_AGENT);
        }
    }
}

// ---------------- host launch ----------------

extern "C" void kernel_launch(void* const* d_in, const int* in_sizes, int n_in,
                              void* d_out, int out_size, void* d_ws, size_t ws_size,
                              hipStream_t stream) {
    const float* feat = (const float*)d_in[0];
    const float* Wih  = (const float*)d_in[1];
    const float* bih  = (const float*)d_in[2];
    const float* Whh  = (const float*)d_in[3];
    const float* bhh  = (const float*)d_in[4];
    const float* Wout = (const float*)d_in[5];
    const float* bout = (const float*)d_in[6];
    const int*   seq  = (const int*)d_in[7];

    char* ws = (char*)d_ws;
    size_t off = 0;
    auto carve = [&](size_t bytes) { char* p = ws + off; off += (bytes + 511) & ~(size_t)511; return p; };
    float*    vbuf   = (float*)   carve((size_t)NEV * Hc * 4);
    int*      head   = (int*)     carve((size_t)NCELL * 4);
    int*      nxt    = (int*)     carve((size_t)NEV * 4);
    int*      cellxy = (int*)     carve((size_t)NEV * 4);
    int*      dep    = (int*)     carve((size_t)NEV * 25 * 4);
    unsigned* flags  = (unsigned*)carve((size_t)NEV * 4);

    hipMemsetAsync(head, 0xFF, (size_t)NCELL * 4, stream);
    hipMemsetAsync(flags, 0, (size_t)NEV * 4, stream);

    k_build<<<(NEV + 255) / 256, 256, 0, stream>>>(feat, head, nxt, cellxy);
    k_resolve<<<(NEV * 25 + 255) / 256, 256, 0, stream>>>(head, nxt, cellxy, dep);

    hipFuncSetAttribute((const void*)step_main,
                        hipFuncAttributeMaxDynamicSharedMemorySize, LDS_BYTES);
    step_main<<<256, 512, LDS_BYTES, stream>>>(feat, Wih, bih, Whh, bhh, Wout, bout,
                                               seq, dep, vbuf, flags, (float*)d_out);
}